// Round 7
// baseline (489.086 us; speedup 1.0000x reference)
//
#include <hip/hip_runtime.h>
#include <math.h>

#define DD   256   // feature dim
#define NN   128   // neighbors
#define NB   572   // drugs
#define NREL 100   // distinct relation rows
#define KT   16    // k-tile
#define NKT  (DD / KT)
#define EH   128   // e-half width per mm block
#define DRS  20    // DRT row stride in floats (16B-aligned, bank-spread)
#define LDRUGS 8   // drugs per linear block

__device__ __forceinline__ float4 ld4(const float* p) {
    return *reinterpret_cast<const float4*>(p);
}

// ---------------------------------------------------------------------------
// Kernel 0: b2 row-sums. Block n sums row n (64 lanes x float4 + shfl).
// ---------------------------------------------------------------------------
__global__ void sum_b2(const float* __restrict__ b2, float* __restrict__ b2s)
{
    const int n = blockIdx.x, t = threadIdx.x;   // 128 blocks x 64 threads
    float4 v = ld4(&b2[n * DD + t * 4]);
    float s = v.x + v.y + v.z + v.w;
    #pragma unroll
    for (int m = 32; m >= 1; m >>= 1) s += __shfl_xor(s, m, 64);
    if (t == 0) b2s[n] = s;
}

// ---------------------------------------------------------------------------
// Kernel 1: matmul + partial logits. Block = (drug b, e-half h). 512 threads.
//  - W2 ROW-sum prologue over this block's row-half:
//      w2s_l[r] = sum_e W2[b][h*EH+r][e]   (collapses the second einsum)
//  - relations deduped (ballot); rows cyclic over 32 groups (tn,+32,+64,+96)
//  - DRT in LDS as [u][k] stride 20 -> ds_read_b128 covers 4 k per row
//  - W1 read DIRECTLY from global (L1/L2 broadcast across waves) - no W1 LDS
//  - partial logit: part[b, h*128+n] = sum_{e in half} relu(A+b1)*w2s
// ---------------------------------------------------------------------------
__global__ __launch_bounds__(512, 4)
void gnn_mm(const float* __restrict__ drug_table,
            const float* __restrict__ rela_table,
            const float* __restrict__ W1,
            const float* __restrict__ b1,
            const float* __restrict__ W2,
            const int*   __restrict__ drug_name,
            const int*   __restrict__ adj_relation,
            float* __restrict__ part)
{
    __shared__ float DRT_l[2][NN * DRS];  // 2 x 10 KB
    __shared__ float d_l[DD];
    __shared__ float w2s_l[EH];
    __shared__ int   rel_l[NN], urel_l[NN], head_l[NN], next_l[NN];
    __shared__ int   map_l[NREL];
    __shared__ int   U_l, c0_l;

    const int bid  = blockIdx.x;
    const int b    = bid >> 1, h = bid & 1;
    const int tid  = threadIdx.x;
    const int lane = tid & 63;
    const int wv   = tid >> 6;

    // ---- setup ----
    if (tid < NN) { rel_l[tid] = adj_relation[b * NN + tid]; head_l[tid] = -1; }
    if (tid < NREL) map_l[tid] = -1;
    if (tid < DD)  d_l[tid] = drug_table[(size_t)drug_name[b] * DD + tid];
    __syncthreads();
    if (tid < NN) map_l[rel_l[tid]] = 1;   // same-value races benign
    __syncthreads();

    // ---- ballot compaction of <=100 marked relations ----
    bool mk = false; int rank = 0, tot = 0;
    if (tid < 128) {
        mk = (tid < NREL) && (map_l[tid] != -1);
        unsigned long long bal = __ballot(mk);
        rank = __popcll(bal & ((1ull << (tid & 63)) - 1));
        tot  = __popcll(bal);
    }
    if (tid < 64) {
        if (mk) { map_l[tid] = rank; urel_l[rank] = tid; }
        if (tid == 0) c0_l = tot;
    }
    __syncthreads();
    if (tid >= 64 && tid < 128) {
        const int base = c0_l;
        if (mk) { map_l[tid] = base + rank; urel_l[base + rank] = tid; }
        if (tid == 64) U_l = base + tot;
    }
    __syncthreads();
    if (tid < NN)
        next_l[tid] = atomicExch(&head_l[map_l[rel_l[tid]]], tid); // order-free
    __syncthreads();

    const int U = U_l;

    const float* W1b = W1 + (size_t)b * DD * DD;
    const float* W2b = W2 + (size_t)b * DD * DD;

    // ---- W2 ROW-sum prologue: w2s_l[r] = sum_e W2[b][h*EH + r][e] ----
    // wave-per-row, float4 coalesced (one full 1KB row per wave-instr)
    for (int r = wv; r < EH; r += 8) {
        float4 v = ld4(&W2b[(size_t)(h * EH + r) * DD + lane * 4]);
        float s = v.x + v.y + v.z + v.w;
        #pragma unroll
        for (int m = 32; m >= 1; m >>= 1) s += __shfl_xor(s, m, 64);
        if (lane == 0) w2s_l[r] = s;
    }

    // ---- k-loop ----
    const int tn = tid >> 4;          // row-group 0..31
    const int td = tid & 15;          // col-thread 0..15
    const bool a0 = (tn      < U);
    const bool a1 = (tn + 32 < U);
    const bool a2 = (tn + 64 < U);
    const bool a3 = (tn + 96 < U);

    float acc[4][8];
    #pragma unroll
    for (int r = 0; r < 4; ++r)
        #pragma unroll
        for (int c = 0; c < 8; ++c) acc[r][c] = 0.f;

    const int su = tid >> 2;          // staging: u row 0..127
    const int kq = tid & 3;           // staging: k quad 0..3

    #define STAGE(buf, kt_)                                                    \
    {                                                                          \
        const int k0_ = (kt_) * KT;                                            \
        if (su < U) {                                                          \
            const float* rr = rela_table + (size_t)urel_l[su] * DD + k0_ + kq*4;\
            float4 v = ld4(rr);                                                \
            float4 w;                                                          \
            w.x = d_l[k0_ + kq * 4 + 0] * v.x;                                 \
            w.y = d_l[k0_ + kq * 4 + 1] * v.y;                                 \
            w.z = d_l[k0_ + kq * 4 + 2] * v.z;                                 \
            w.w = d_l[k0_ + kq * 4 + 3] * v.w;                                 \
            *reinterpret_cast<float4*>(&DRT_l[buf][su * DRS + kq * 4]) = w;    \
        }                                                                      \
    }

    #define FMA8(j, a)                                                         \
        { acc[j][0] = fmaf(a, ww[0], acc[j][0]);                               \
          acc[j][1] = fmaf(a, ww[1], acc[j][1]);                               \
          acc[j][2] = fmaf(a, ww[2], acc[j][2]);                               \
          acc[j][3] = fmaf(a, ww[3], acc[j][3]);                               \
          acc[j][4] = fmaf(a, ww[4], acc[j][4]);                               \
          acc[j][5] = fmaf(a, ww[5], acc[j][5]);                               \
          acc[j][6] = fmaf(a, ww[6], acc[j][6]);                               \
          acc[j][7] = fmaf(a, ww[7], acc[j][7]); }

    STAGE(0, 0);
    __syncthreads();

    for (int kt = 0; kt < NKT; ++kt) {
        const int cur = kt & 1;
        if (kt + 1 < NKT) STAGE(cur ^ 1, kt + 1);

        const float* W1t = W1b + (size_t)(kt * KT) * DD + h * EH;

        #pragma unroll
        for (int q = 0; q < 4; ++q) {          // 4 k's per iteration
            float4 av0, av1, av2, av3;
            if (a0) av0 = ld4(&DRT_l[cur][(tn     ) * DRS + q * 4]);
            if (a1) av1 = ld4(&DRT_l[cur][(tn + 32) * DRS + q * 4]);
            if (a2) av2 = ld4(&DRT_l[cur][(tn + 64) * DRS + q * 4]);
            if (a3) av3 = ld4(&DRT_l[cur][(tn + 96) * DRS + q * 4]);

            #define DOK(KC, C)                                                 \
            {   const float* wp = W1t + (size_t)(q * 4 + KC) * DD;             \
                float4 w0 = ld4(&wp[td * 4]);                                  \
                float4 w1 = ld4(&wp[64 + td * 4]);                             \
                float ww[8] = {w0.x, w0.y, w0.z, w0.w, w1.x, w1.y, w1.z, w1.w};\
                if (a0) FMA8(0, av0.C);                                        \
                if (a1) FMA8(1, av1.C);                                        \
                if (a2) FMA8(2, av2.C);                                        \
                if (a3) FMA8(3, av3.C); }

            DOK(0, x) DOK(1, y) DOK(2, z) DOK(3, w)
            #undef DOK
        }
        __syncthreads();
    }
    #undef STAGE

    // ---- partial logits via per-u linked lists (static acc indexing) ----
    float wreg[8];
    {
        float4 t0 = ld4(&w2s_l[td * 4]);
        float4 t1 = ld4(&w2s_l[64 + td * 4]);
        wreg[0]=t0.x; wreg[1]=t0.y; wreg[2]=t0.z; wreg[3]=t0.w;
        wreg[4]=t1.x; wreg[5]=t1.y; wreg[6]=t1.z; wreg[7]=t1.w;
    }
    #pragma unroll
    for (int r = 0; r < 4; ++r) {
        const int u = tn + 32 * r;
        int n = (u < U) ? head_l[u] : -1;
        while (n >= 0) {
            const float* bp = b1 + (size_t)n * DD + h * EH;
            float4 b0 = ld4(&bp[td * 4]);
            float4 b1v = ld4(&bp[64 + td * 4]);
            float s = fmaxf(acc[r][0] + b0.x,  0.f) * wreg[0]
                    + fmaxf(acc[r][1] + b0.y,  0.f) * wreg[1]
                    + fmaxf(acc[r][2] + b0.z,  0.f) * wreg[2]
                    + fmaxf(acc[r][3] + b0.w,  0.f) * wreg[3]
                    + fmaxf(acc[r][4] + b1v.x, 0.f) * wreg[4]
                    + fmaxf(acc[r][5] + b1v.y, 0.f) * wreg[5]
                    + fmaxf(acc[r][6] + b1v.z, 0.f) * wreg[6]
                    + fmaxf(acc[r][7] + b1v.w, 0.f) * wreg[7];
            #pragma unroll
            for (int m = 8; m >= 1; m >>= 1) s += __shfl_xor(s, m, 16);
            if (td == 0) part[(size_t)b * 256 + h * NN + n] = s;
            n = next_l[n];
        }
    }
    #undef FMA8
}

// ---------------------------------------------------------------------------
// Kernel 2: per drug — combine partial logits, softmax, sparse ent gather,
// build x = [w_ent | d] in workspace.
// ---------------------------------------------------------------------------
__global__ __launch_bounds__(256)
void gnn_gather(const float* __restrict__ drug_table,
                const float* __restrict__ ent_table,
                const int*   __restrict__ drug_name,
                const int*   __restrict__ adj_tail,
                const float* __restrict__ part,
                const float* __restrict__ b2s_g,
                float* __restrict__ xbuf)
{
    __shared__ float score_l[NN];
    __shared__ int   tail_l[NN];

    const int b = blockIdx.x, tid = threadIdx.x;

    if (tid < NN) {
        tail_l[tid]  = adj_tail[b * NN + tid];
        score_l[tid] = part[(size_t)b * 256 + tid]
                     + part[(size_t)b * 256 + NN + tid] + b2s_g[tid];
    }
    __syncthreads();

    if (tid < 64) {
        float l0 = score_l[tid], l1 = score_l[tid + 64];
        float M = fmaxf(l0, l1);
        #pragma unroll
        for (int m = 32; m >= 1; m >>= 1) M = fmaxf(M, __shfl_xor(M, m, 64));
        float e0 = expf(l0 - M), e1 = expf(l1 - M);
        float S = e0 + e1;
        #pragma unroll
        for (int m = 32; m >= 1; m >>= 1) S += __shfl_xor(S, m, 64);
        float inv = 1.f / S;
        score_l[tid]      = e0 * inv;
        score_l[tid + 64] = e1 * inv;
    }
    __syncthreads();

    // sparse gather (softmax ~one-hot; skipped mass < 1.3e-7)
    float w = 0.f;
    for (int n = 0; n < NN; ++n) {
        float s = score_l[n];
        if (s > 1e-9f)
            w = fmaf(s, ent_table[(size_t)tail_l[n] * DD + tid], w);
    }
    xbuf[(size_t)b * 512 + tid]       = w;
    xbuf[(size_t)b * 512 + 256 + tid] = drug_table[(size_t)drug_name[b] * DD + tid];
}

// ---------------------------------------------------------------------------
// Kernel 3: batched linear — LDRUGS drugs per block amortize lin_w reads.
// ---------------------------------------------------------------------------
__global__ __launch_bounds__(256)
void gnn_lin(const float* __restrict__ lin_w,
             const float* __restrict__ lin_b,
             const float* __restrict__ xbuf,
             float* __restrict__ Y)
{
    __shared__ float x_l[LDRUGS * 512];   // 16 KB

    const int g = blockIdx.x, tid = threadIdx.x;
    const int b0 = g * LDRUGS;

    #pragma unroll
    for (int i = 0; i < LDRUGS * 2; ++i) {
        int f = tid + i * 256;
        *reinterpret_cast<float4*>(&x_l[f * 4]) = ld4(&xbuf[(size_t)b0 * 512 + f * 4]);
    }
    __syncthreads();

    const float* lw = lin_w + (size_t)tid * 512;
    float dot[LDRUGS];
    #pragma unroll
    for (int d = 0; d < LDRUGS; ++d) dot[d] = 0.f;

    for (int k4 = 0; k4 < 128; ++k4) {
        float4 wv = ld4(&lw[k4 * 4]);
        #pragma unroll
        for (int d = 0; d < LDRUGS; ++d) {
            float4 xv = ld4(&x_l[d * 512 + k4 * 4]);
            dot[d] += wv.x * xv.x + wv.y * xv.y + wv.z * xv.z + wv.w * xv.w;
        }
    }

    const float bb = lin_b[tid];
    #pragma unroll
    for (int d = 0; d < LDRUGS; ++d) {
        if (b0 + d < NB)
            Y[(size_t)(b0 + d) * DD + tid] = fmaxf(dot[d] + bb, 0.f);
    }
}

// ---------------------------------------------------------------------------
// BN stats (biased variance) + apply
// ---------------------------------------------------------------------------
__global__ void bn_stats(const float* __restrict__ Y, float* __restrict__ stats)
{
    int d = blockIdx.x, t = threadIdx.x;  // 64 threads
    float s = 0.f, ss = 0.f;
    for (int b = t; b < NB; b += 64) {
        float v = Y[(size_t)b * DD + d];
        s += v; ss += v * v;
    }
    #pragma unroll
    for (int m = 32; m >= 1; m >>= 1) {
        s  += __shfl_xor(s, m, 64);
        ss += __shfl_xor(ss, m, 64);
    }
    if (t == 0) {
        float mean = s * (1.f / NB);
        float var  = ss * (1.f / NB) - mean * mean;
        stats[d]      = mean;
        stats[DD + d] = rsqrtf(var + 1e-5f);
    }
}

__global__ void bn_apply(float* __restrict__ Y, const float* __restrict__ stats,
                         const float* __restrict__ gamma, const float* __restrict__ beta)
{
    int b = blockIdx.x, t = threadIdx.x;
    float mean = stats[t], inv = stats[DD + t];
    float v = Y[(size_t)b * DD + t];
    Y[(size_t)b * DD + t] = gamma[t] * (v - mean) * inv + beta[t];
}

extern "C" void kernel_launch(void* const* d_in, const int* in_sizes, int n_in,
                              void* d_out, int out_size, void* d_ws, size_t ws_size,
                              hipStream_t stream)
{
    const float* drug_table = (const float*)d_in[0];
    const float* rela_table = (const float*)d_in[1];
    const float* ent_table  = (const float*)d_in[2];
    const float* W1         = (const float*)d_in[3];
    const float* b1         = (const float*)d_in[4];
    const float* W2         = (const float*)d_in[5];
    const float* b2         = (const float*)d_in[6];
    const float* lin_w      = (const float*)d_in[7];
    const float* lin_b      = (const float*)d_in[8];
    const float* bn_g       = (const float*)d_in[9];
    const float* bn_b       = (const float*)d_in[10];
    const int*   drug_name  = (const int*)d_in[11];
    const int*   adj_tail   = (const int*)d_in[12];
    const int*   adj_rel    = (const int*)d_in[13];
    float* out = (float*)d_out;

    const int NBP = ((NB + LDRUGS - 1) / LDRUGS) * LDRUGS;   // 576
    float* b2s   = (float*)d_ws;                   // NN
    float* part  = b2s + NN;                       // NB*256
    float* xbuf  = part + (size_t)NB * 256;        // NBP*512
    float* stats = xbuf + (size_t)NBP * 512;       // 2*DD

    sum_b2<<<NN, 64, 0, stream>>>(b2, b2s);
    gnn_mm<<<2 * NB, 512, 0, stream>>>(drug_table, rela_table, W1, b1, W2,
                                       drug_name, adj_rel, part);
    gnn_gather<<<NB, 256, 0, stream>>>(drug_table, ent_table, drug_name,
                                       adj_tail, part, b2s, xbuf);
    gnn_lin<<<NBP / LDRUGS, 256, 0, stream>>>(lin_w, lin_b, xbuf, out);
    bn_stats<<<DD, 64, 0, stream>>>(out, stats);
    bn_apply<<<NB, DD, 0, stream>>>(out, stats, bn_g, bn_b);
}

// Round 8
// 168.371 us; speedup vs baseline: 2.9048x; 2.9048x over previous
//
#include <hip/hip_runtime.h>
#include <math.h>

#define DD   256   // feature dim
#define NN   128   // neighbors
#define NB   572   // drugs
#define NREL 100   // distinct relation rows
#define KS   32    // k-step (MFMA K)
#define NKS  (DD / KS)
#define AS   40    // A lds row stride (halves): banks spread, 16B aligned
#define BS   40    // B lds row stride (halves)
#define PS   260   // P scratch stride (f32)
#define LDRUGS 8

typedef _Float16 h8 __attribute__((ext_vector_type(8)));
typedef _Float16 h2 __attribute__((ext_vector_type(2)));
typedef float    f4 __attribute__((ext_vector_type(4)));

__device__ __forceinline__ float4 ld4(const float* p) {
    return *reinterpret_cast<const float4*>(p);
}
__device__ __forceinline__ void split16(float x, _Float16& hi, _Float16& lo) {
    hi = (_Float16)x;
    lo = (_Float16)(x - (float)hi);
}

// ---------------------------------------------------------------------------
// b2 row-sums
// ---------------------------------------------------------------------------
__global__ void sum_b2(const float* __restrict__ b2, float* __restrict__ b2s)
{
    const int n = blockIdx.x, t = threadIdx.x;   // 128 x 64
    float4 v = ld4(&b2[n * DD + t * 4]);
    float s = v.x + v.y + v.z + v.w;
    #pragma unroll
    for (int m = 32; m >= 1; m >>= 1) s += __shfl_xor(s, m, 64);
    if (t == 0) b2s[n] = s;
}

// ---------------------------------------------------------------------------
// Main per-drug kernel (MFMA f16 hi/lo split):
//   P = R_u @ (d.W1)  via mfma_f32_16x16x32_f16, 3 products (hh, lh, hl)
//   fused W2 row-sums; logits; softmax; sparse ent gather; x -> xbuf
// ---------------------------------------------------------------------------
__global__ __launch_bounds__(512, 2)
void gnn_mm(const float* __restrict__ drug_table,
            const float* __restrict__ rela_table,
            const float* __restrict__ ent_table,
            const float* __restrict__ W1,
            const float* __restrict__ b1,
            const float* __restrict__ W2,
            const int*   __restrict__ drug_name,
            const int*   __restrict__ adj_tail,
            const int*   __restrict__ adj_relation,
            const float* __restrict__ b2s_g,
            float* __restrict__ xbuf)
{
    __shared__ __align__(16) _Float16 A_l[2][2][128 * AS];  // 40.96 KB [buf][hi/lo]
    __shared__ __align__(16) _Float16 B_l[2][2][256 * BS];  // 81.92 KB (P overlays)
    __shared__ float d_l[DD];
    __shared__ float w2s_l[DD];
    __shared__ float b2s_l[NN];
    __shared__ float score_l[NN];
    __shared__ int   rel_l[NN], tail_l[NN], urel_l[NN], head_l[NN], next_l[NN];
    __shared__ int   map_l[NREL];
    __shared__ int   U_l, c0_l;

    float* Pl = reinterpret_cast<float*>(&B_l[0][0][0]);    // 32*260*4 = 33.3 KB

    const int b    = blockIdx.x;
    const int tid  = threadIdx.x;
    const int lane = tid & 63;
    const int wv   = tid >> 6;
    const int rg   = wv >> 2;          // wave row-group 0..1
    const int cg   = wv & 3;           // wave col-group 0..3
    const int r16  = lane & 15;
    const int g8   = (lane >> 4) * 8;

    // ---- setup ----
    if (tid < NN) {
        rel_l[tid]  = adj_relation[b * NN + tid];
        tail_l[tid] = adj_tail[b * NN + tid];
        head_l[tid] = -1;
        b2s_l[tid]  = b2s_g[tid];
    }
    if (tid < NREL) map_l[tid] = -1;
    if (tid < DD)  d_l[tid] = drug_table[(size_t)drug_name[b] * DD + tid];
    __syncthreads();
    if (tid < NN) map_l[rel_l[tid]] = 1;
    __syncthreads();

    // ---- ballot compaction ----
    bool mk = false; int rank = 0, tot = 0;
    if (tid < 128) {
        mk = (tid < NREL) && (map_l[tid] != -1);
        unsigned long long bal = __ballot(mk);
        rank = __popcll(bal & ((1ull << (tid & 63)) - 1));
        tot  = __popcll(bal);
    }
    if (tid < 64) {
        if (mk) { map_l[tid] = rank; urel_l[rank] = tid; }
        if (tid == 0) c0_l = tot;
    }
    __syncthreads();
    if (tid >= 64 && tid < 128) {
        const int base = c0_l;
        if (mk) { map_l[tid] = base + rank; urel_l[base + rank] = tid; }
        if (tid == 64) U_l = base + tot;
    }
    __syncthreads();
    if (tid < NN)
        next_l[tid] = atomicExch(&head_l[map_l[rel_l[tid]]], tid);
    __syncthreads();

    const int U   = U_l;
    const int NRT = (U + 31) >> 5;     // row-tiles of 32 (1..4)

    const float* W1b = W1 + (size_t)b * DD * DD;
    const float* W2b = W2 + (size_t)b * DD * DD;

    // staging maps
    const int sau = tid >> 2;          // A: u row 0..127
    const int sak = (tid & 3) * 8;     // A: k offset
    const int skp = (tid >> 5) & 15;   // B: k pair -> k = 2*skp
    const int sel = tid & 31;          // B: e lane

    // zero-pad A rows U..NRT*32 (both buffers, hi+lo) so padded MFMA rows are 0
    for (int x = tid; x < (NRT * 32 - U) * 16; x += 512) {
        int r = U + (x >> 4), c = (x & 15) * 2;
        h2 z = {(_Float16)0.f, (_Float16)0.f};
        *(h2*)&A_l[0][0][r * AS + c] = z;  *(h2*)&A_l[0][1][r * AS + c] = z;
        *(h2*)&A_l[1][0][r * AS + c] = z;  *(h2*)&A_l[1][1][r * AS + c] = z;
    }
    __syncthreads();

    // ---- prologue: stage kt=0 into buf 0 ----
    {
        const float da = d_l[2 * skp], db = d_l[2 * skp + 1];
        const float* w1p0 = W1b + (size_t)(2 * skp) * DD + sel;
        const float* w1p1 = w1p0 + DD;
        #pragma unroll
        for (int i = 0; i < 8; ++i) {
            int e = sel + 32 * i;
            _Float16 h0, l0, h1, l1;
            split16(w1p0[32 * i] * da, h0, l0);
            split16(w1p1[32 * i] * db, h1, l1);
            *(h2*)&B_l[0][0][e * BS + 2 * skp] = {h0, h1};
            *(h2*)&B_l[0][1][e * BS + 2 * skp] = {l0, l1};
        }
        if (sau < U) {
            const float* rr = rela_table + (size_t)urel_l[sau] * DD + sak;
            float4 a0 = ld4(rr), a1 = ld4(rr + 4);
            float av[8] = {a0.x,a0.y,a0.z,a0.w, a1.x,a1.y,a1.z,a1.w};
            #pragma unroll
            for (int q = 0; q < 4; ++q) {
                _Float16 h0, l0, h1, l1;
                split16(av[2*q],   h0, l0);
                split16(av[2*q+1], h1, l1);
                *(h2*)&A_l[0][0][sau * AS + sak + 2*q] = {h0, h1};
                *(h2*)&A_l[0][1][sau * AS + sak + 2*q] = {l0, l1};
            }
        }
    }
    __syncthreads();

    f4 acc[2][2][4];
    #pragma unroll
    for (int p = 0; p < 2; ++p)
        #pragma unroll
        for (int sr = 0; sr < 2; ++sr)
            #pragma unroll
            for (int sc = 0; sc < 4; ++sc)
                acc[p][sr][sc] = {0.f, 0.f, 0.f, 0.f};

    // ---- k-loop ----
    for (int kt = 0; kt < NKS; ++kt) {
        const int cur  = kt & 1;
        const bool more = (kt + 1 < NKS);
        const int k1 = (kt + 1) * KS;

        // (1) issue next-tile loads (regs) — T14 async split
        float rb0[8], rb1[8]; float4 ra0, ra1;
        if (more) {
            const float* w1p0 = W1b + (size_t)(k1 + 2 * skp) * DD + sel;
            const float* w1p1 = w1p0 + DD;
            #pragma unroll
            for (int i = 0; i < 8; ++i) { rb0[i] = w1p0[32*i]; rb1[i] = w1p1[32*i]; }
            if (sau < U) {
                const float* rr = rela_table + (size_t)urel_l[sau] * DD + k1 + sak;
                ra0 = ld4(rr); ra1 = ld4(rr + 4);
            }
        }
        // W2 fused row-sum loads (rows wv*32 + kt*4 + r)
        float4 rw[4];
        #pragma unroll
        for (int r = 0; r < 4; ++r)
            rw[r] = ld4(&W2b[(size_t)(wv * 32 + kt * 4 + r) * DD + lane * 4]);

        // (2) compute on buf cur
        h8 bh[4], bl[4];
        #pragma unroll
        for (int sc = 0; sc < 4; ++sc) {
            int coff = (cg * 64 + sc * 16 + r16) * BS + g8;
            bh[sc] = *(const h8*)&B_l[cur][0][coff];
            bl[sc] = *(const h8*)&B_l[cur][1][coff];
        }
        #pragma unroll
        for (int p = 0; p < 2; ++p) {
            const int rp = rg + 2 * p;
            if (rp < NRT) {
                #pragma unroll
                for (int sr = 0; sr < 2; ++sr) {
                    int aoff = (rp * 32 + sr * 16 + r16) * AS + g8;
                    h8 ah = *(const h8*)&A_l[cur][0][aoff];
                    h8 al = *(const h8*)&A_l[cur][1][aoff];
                    #pragma unroll
                    for (int sc = 0; sc < 4; ++sc) {
                        acc[p][sr][sc] = __builtin_amdgcn_mfma_f32_16x16x32_f16(ah, bh[sc], acc[p][sr][sc], 0, 0, 0);
                        acc[p][sr][sc] = __builtin_amdgcn_mfma_f32_16x16x32_f16(al, bh[sc], acc[p][sr][sc], 0, 0, 0);
                        acc[p][sr][sc] = __builtin_amdgcn_mfma_f32_16x16x32_f16(ah, bl[sc], acc[p][sr][sc], 0, 0, 0);
                    }
                }
            }
        }

        // (3) W2 reduce + write
        #pragma unroll
        for (int r = 0; r < 4; ++r) {
            float s = rw[r].x + rw[r].y + rw[r].z + rw[r].w;
            #pragma unroll
            for (int m = 32; m >= 1; m >>= 1) s += __shfl_xor(s, m, 64);
            if (lane == 0) w2s_l[wv * 32 + kt * 4 + r] = s;
        }

        // (4) write staged tile into buf cur^1
        if (more) {
            const int nb = cur ^ 1;
            const float da = d_l[k1 + 2 * skp], db = d_l[k1 + 2 * skp + 1];
            #pragma unroll
            for (int i = 0; i < 8; ++i) {
                int e = sel + 32 * i;
                _Float16 h0, l0, h1, l1;
                split16(rb0[i] * da, h0, l0);
                split16(rb1[i] * db, h1, l1);
                *(h2*)&B_l[nb][0][e * BS + 2 * skp] = {h0, h1};
                *(h2*)&B_l[nb][1][e * BS + 2 * skp] = {l0, l1};
            }
            if (sau < U) {
                float av[8] = {ra0.x,ra0.y,ra0.z,ra0.w, ra1.x,ra1.y,ra1.z,ra1.w};
                #pragma unroll
                for (int q = 0; q < 4; ++q) {
                    _Float16 h0, l0, h1, l1;
                    split16(av[2*q],   h0, l0);
                    split16(av[2*q+1], h1, l1);
                    *(h2*)&A_l[nb][0][sau * AS + sak + 2*q] = {h0, h1};
                    *(h2*)&A_l[nb][1][sau * AS + sak + 2*q] = {l0, l1};
                }
            }
        }
        __syncthreads();
    }

    // ---- epilogue: per row-tile, acc -> P (LDS, overlays B) -> logits ----
    const int td16 = tid & 15;
    const int ug   = tid >> 4;         // 0..31
    float wr[16];
    #pragma unroll
    for (int j = 0; j < 4; ++j) {
        float4 t = ld4(&w2s_l[td16 * 16 + j * 4]);
        wr[j*4+0] = t.x; wr[j*4+1] = t.y; wr[j*4+2] = t.z; wr[j*4+3] = t.w;
    }

    #pragma unroll
    for (int rt = 0; rt < 4; ++rt) {
        if (rt < NRT) {
            __syncthreads();
            if (rg == (rt & 1)) {
                const int p = rt >> 1;
                #pragma unroll
                for (int sr = 0; sr < 2; ++sr)
                    #pragma unroll
                    for (int sc = 0; sc < 4; ++sc)
                        #pragma unroll
                        for (int j = 0; j < 4; ++j)
                            Pl[(sr*16 + (lane>>4)*4 + j) * PS + cg*64 + sc*16 + r16] =
                                acc[p][sr][sc][j];
            }
            __syncthreads();
            const int u = rt * 32 + ug;
            if (u < U) {
                int n = head_l[u];
                while (n >= 0) {
                    const float* bp = b1 + (size_t)n * DD;
                    float s = 0.f;
                    #pragma unroll
                    for (int j = 0; j < 4; ++j) {
                        float4 pv = ld4(&Pl[ug * PS + td16 * 16 + j * 4]);
                        float4 bv = ld4(&bp[td16 * 16 + j * 4]);
                        s += fmaxf(pv.x + bv.x, 0.f) * wr[j*4+0]
                           + fmaxf(pv.y + bv.y, 0.f) * wr[j*4+1]
                           + fmaxf(pv.z + bv.z, 0.f) * wr[j*4+2]
                           + fmaxf(pv.w + bv.w, 0.f) * wr[j*4+3];
                    }
                    #pragma unroll
                    for (int m = 8; m >= 1; m >>= 1) s += __shfl_xor(s, m, 16);
                    if (td16 == 0) score_l[n] = s + b2s_l[n];
                    n = next_l[n];
                }
            }
        }
    }
    __syncthreads();

    // ---- softmax (exact f32, wave 0) ----
    if (tid < 64) {
        float l0 = score_l[tid], l1 = score_l[tid + 64];
        float M = fmaxf(l0, l1);
        #pragma unroll
        for (int m = 32; m >= 1; m >>= 1) M = fmaxf(M, __shfl_xor(M, m, 64));
        float e0 = expf(l0 - M), e1 = expf(l1 - M);
        float S = e0 + e1;
        #pragma unroll
        for (int m = 32; m >= 1; m >>= 1) S += __shfl_xor(S, m, 64);
        float inv = 1.f / S;
        score_l[tid]      = e0 * inv;
        score_l[tid + 64] = e1 * inv;
    }
    __syncthreads();

    // ---- sparse ent gather + x write ----
    if (tid < DD) {
        float w = 0.f;
        for (int n = 0; n < NN; ++n) {
            float s = score_l[n];
            if (s > 1e-9f)
                w = fmaf(s, ent_table[(size_t)tail_l[n] * DD + tid], w);
        }
        xbuf[(size_t)b * 512 + tid]       = w;
        xbuf[(size_t)b * 512 + 256 + tid] = d_l[tid];
    }
}

// ---------------------------------------------------------------------------
// batched linear
// ---------------------------------------------------------------------------
__global__ __launch_bounds__(256)
void gnn_lin(const float* __restrict__ lin_w,
             const float* __restrict__ lin_b,
             const float* __restrict__ xbuf,
             float* __restrict__ Y)
{
    __shared__ float x_l[LDRUGS * 512];

    const int g = blockIdx.x, tid = threadIdx.x;
    const int b0 = g * LDRUGS;

    #pragma unroll
    for (int i = 0; i < LDRUGS * 2; ++i) {
        int f = tid + i * 256;
        *reinterpret_cast<float4*>(&x_l[f * 4]) = ld4(&xbuf[(size_t)b0 * 512 + f * 4]);
    }
    __syncthreads();

    const float* lw = lin_w + (size_t)tid * 512;
    float dot[LDRUGS];
    #pragma unroll
    for (int d = 0; d < LDRUGS; ++d) dot[d] = 0.f;

    for (int k4 = 0; k4 < 128; ++k4) {
        float4 wv = ld4(&lw[k4 * 4]);
        #pragma unroll
        for (int d = 0; d < LDRUGS; ++d) {
            float4 xv = ld4(&x_l[d * 512 + k4 * 4]);
            dot[d] += wv.x * xv.x + wv.y * xv.y + wv.z * xv.z + wv.w * xv.w;
        }
    }

    const float bb = lin_b[tid];
    #pragma unroll
    for (int d = 0; d < LDRUGS; ++d) {
        if (b0 + d < NB)
            Y[(size_t)(b0 + d) * DD + tid] = fmaxf(dot[d] + bb, 0.f);
    }
}

// ---------------------------------------------------------------------------
// BN stats + apply
// ---------------------------------------------------------------------------
__global__ void bn_stats(const float* __restrict__ Y, float* __restrict__ stats)
{
    int d = blockIdx.x, t = threadIdx.x;
    float s = 0.f, ss = 0.f;
    for (int b = t; b < NB; b += 64) {
        float v = Y[(size_t)b * DD + d];
        s += v; ss += v * v;
    }
    #pragma unroll
    for (int m = 32; m >= 1; m >>= 1) {
        s  += __shfl_xor(s, m, 64);
        ss += __shfl_xor(ss, m, 64);
    }
    if (t == 0) {
        float mean = s * (1.f / NB);
        float var  = ss * (1.f / NB) - mean * mean;
        stats[d]      = mean;
        stats[DD + d] = rsqrtf(var + 1e-5f);
    }
}

__global__ void bn_apply(float* __restrict__ Y, const float* __restrict__ stats,
                         const float* __restrict__ gamma, const float* __restrict__ beta)
{
    int b = blockIdx.x, t = threadIdx.x;
    float mean = stats[t], inv = stats[DD + t];
    float v = Y[(size_t)b * DD + t];
    Y[(size_t)b * DD + t] = gamma[t] * (v - mean) * inv + beta[t];
}

extern "C" void kernel_launch(void* const* d_in, const int* in_sizes, int n_in,
                              void* d_out, int out_size, void* d_ws, size_t ws_size,
                              hipStream_t stream)
{
    const float* drug_table = (const float*)d_in[0];
    const float* rela_table = (const float*)d_in[1];
    const float* ent_table  = (const float*)d_in[2];
    const float* W1         = (const float*)d_in[3];
    const float* b1         = (const float*)d_in[4];
    const float* W2         = (const float*)d_in[5];
    const float* b2         = (const float*)d_in[6];
    const float* lin_w      = (const float*)d_in[7];
    const float* lin_b      = (const float*)d_in[8];
    const float* bn_g       = (const float*)d_in[9];
    const float* bn_b       = (const float*)d_in[10];
    const int*   drug_name  = (const int*)d_in[11];
    const int*   adj_tail   = (const int*)d_in[12];
    const int*   adj_rel    = (const int*)d_in[13];
    float* out = (float*)d_out;

    const int NBP = ((NB + LDRUGS - 1) / LDRUGS) * LDRUGS;   // 576
    float* b2s   = (float*)d_ws;                   // NN
    float* xbuf  = b2s + NN;                       // NBP*512
    float* stats = xbuf + (size_t)NBP * 512;       // 2*DD

    sum_b2<<<NN, 64, 0, stream>>>(b2, b2s);
    gnn_mm<<<NB, 512, 0, stream>>>(drug_table, rela_table, ent_table,
                                   W1, b1, W2, drug_name, adj_tail, adj_rel,
                                   b2s, xbuf);
    gnn_lin<<<NBP / LDRUGS, 256, 0, stream>>>(lin_w, lin_b, xbuf, out);
    bn_stats<<<DD, 64, 0, stream>>>(out, stats);
    bn_apply<<<NB, DD, 0, stream>>>(out, stats, bn_g, bn_b);
}

// Round 9
// 155.441 us; speedup vs baseline: 3.1464x; 1.0832x over previous
//
#include <hip/hip_runtime.h>
#include <math.h>

#define DD   256   // feature dim
#define NN   128   // neighbors
#define NB   572   // drugs
#define NREL 100   // distinct relation rows
#define KS   32    // k-step (MFMA K)
#define NKS  (DD / KS)
#define RS   72    // paired-row stride in halves: [32 hi][32 lo][8 pad] -> 36 words, 2-way banks
#define PS   260   // P scratch stride (f32)
#define LDRUGS 8

typedef _Float16 h8 __attribute__((ext_vector_type(8)));
typedef _Float16 h2 __attribute__((ext_vector_type(2)));
typedef float    f4 __attribute__((ext_vector_type(4)));

__device__ __forceinline__ float4 ld4(const float* p) {
    return *reinterpret_cast<const float4*>(p);
}
__device__ __forceinline__ void split16(float x, _Float16& hi, _Float16& lo) {
    hi = (_Float16)x;
    lo = (_Float16)(x - (float)hi);
}

// ---------------------------------------------------------------------------
// b2 row-sums
// ---------------------------------------------------------------------------
__global__ void sum_b2(const float* __restrict__ b2, float* __restrict__ b2s)
{
    const int n = blockIdx.x, t = threadIdx.x;   // 128 x 64
    float4 v = ld4(&b2[n * DD + t * 4]);
    float s = v.x + v.y + v.z + v.w;
    #pragma unroll
    for (int m = 32; m >= 1; m >>= 1) s += __shfl_xor(s, m, 64);
    if (t == 0) b2s[n] = s;
}

// ---------------------------------------------------------------------------
// Main per-drug kernel (MFMA f16 hi/lo 3-product), 1024 threads / 16 waves.
//   A = R_u [u][k], B = (d*W1)^T-fragments from [e][k] paired hi/lo LDS.
//   Fused W2 row-sums; logits; softmax; sparse ent gather; x -> xbuf.
// ---------------------------------------------------------------------------
__global__ __launch_bounds__(1024, 1)
void gnn_mm(const float* __restrict__ drug_table,
            const float* __restrict__ rela_table,
            const float* __restrict__ ent_table,
            const float* __restrict__ W1,
            const float* __restrict__ b1,
            const float* __restrict__ W2,
            const int*   __restrict__ drug_name,
            const int*   __restrict__ adj_tail,
            const int*   __restrict__ adj_relation,
            const float* __restrict__ b2s_g,
            float* __restrict__ xbuf)
{
    __shared__ __align__(16) _Float16 A_l[2][128 * RS];  // 36.9 KB
    __shared__ __align__(16) _Float16 B_l[2][256 * RS];  // 73.7 KB (P overlays [0])
    __shared__ float d_l[DD];
    __shared__ float w2s_l[DD];
    __shared__ float b2s_l[NN];
    __shared__ float score_l[NN];
    __shared__ int   rel_l[NN], tail_l[NN], urel_l[NN], head_l[NN], next_l[NN];
    __shared__ int   map_l[NREL];
    __shared__ int   U_l, c0_l;

    float* Pl = reinterpret_cast<float*>(&B_l[0][0]);    // 32*260*4 = 33.3 KB

    const int b    = blockIdx.x;
    const int tid  = threadIdx.x;
    const int lane = tid & 63;
    const int wv   = tid >> 6;          // 0..15
    const int rg   = wv >> 2;           // row-tile 0..3
    const int cg   = wv & 3;            // col-group 0..3 (64 e each)
    const int r16  = lane & 15;
    const int g8   = (lane >> 4) * 8;

    // ---- setup ----
    if (tid < NN) {
        rel_l[tid]  = adj_relation[b * NN + tid];
        tail_l[tid] = adj_tail[b * NN + tid];
        head_l[tid] = -1;
        b2s_l[tid]  = b2s_g[tid];
    }
    if (tid < NREL) map_l[tid] = -1;
    if (tid < DD)  d_l[tid] = drug_table[(size_t)drug_name[b] * DD + tid];
    __syncthreads();
    if (tid < NN) map_l[rel_l[tid]] = 1;
    __syncthreads();

    // ---- ballot compaction (waves 0-1) ----
    bool mk = false; int rank = 0, tot = 0;
    if (tid < 128) {
        mk = (tid < NREL) && (map_l[tid] != -1);
        unsigned long long bal = __ballot(mk);
        rank = __popcll(bal & ((1ull << (tid & 63)) - 1));
        tot  = __popcll(bal);
    }
    if (tid < 64) {
        if (mk) { map_l[tid] = rank; urel_l[rank] = tid; }
        if (tid == 0) c0_l = tot;
    }
    __syncthreads();
    if (tid >= 64 && tid < 128) {
        const int base = c0_l;
        if (mk) { map_l[tid] = base + rank; urel_l[base + rank] = tid; }
        if (tid == 64) U_l = base + tot;
    }
    __syncthreads();
    if (tid < NN)
        next_l[tid] = atomicExch(&head_l[map_l[rel_l[tid]]], tid);
    __syncthreads();

    const int U   = U_l;
    const int NRT = (U + 31) >> 5;      // 1..4 row-tiles of 32

    const float* W1b = W1 + (size_t)b * DD * DD;
    const float* W2b = W2 + (size_t)b * DD * DD;

    // ---- zero-pad A rows U..NRT*32-1 (hi+lo halves 0..63), both buffers ----
    {
        const int padrows = NRT * 32 - U;
        h2 z = {(_Float16)0.f, (_Float16)0.f};
        for (int x = tid; x < padrows * 32; x += 1024) {
            int r = U + (x >> 5), m = (x & 31) * 2;
            *(h2*)&A_l[0][r * RS + m] = z;
            *(h2*)&A_l[1][r * RS + m] = z;
        }
    }

    // staging maps
    const int kp  = tid & 15;           // B: k-pair
    const int eg  = tid >> 4;           // B: e-quad 0..63
    const int sau = tid >> 3;           // A: u row 0..127
    const int sak = (tid & 7) * 4;      // A: k-quad offset

    float4 rbA, rbB, raA;

    #define STAGE_LOAD(kt_) {                                                  \
        const int k_ = (kt_) * KS + 2 * kp;                                    \
        rbA = ld4(&W1b[(size_t)k_ * DD + eg * 4]);                             \
        rbB = ld4(&W1b[(size_t)(k_ + 1) * DD + eg * 4]);                       \
        if (sau < U)                                                           \
            raA = ld4(&rela_table[(size_t)urel_l[sau] * DD + (kt_) * KS + sak]);\
    }

    #define STAGE_WRITE(buf, kt_) {                                            \
        const int k_ = (kt_) * KS + 2 * kp;                                    \
        const float da = d_l[k_], db = d_l[k_ + 1];                            \
        const float va[4] = {rbA.x, rbA.y, rbA.z, rbA.w};                      \
        const float vb[4] = {rbB.x, rbB.y, rbB.z, rbB.w};                      \
        for (int i = 0; i < 4; ++i) {                                          \
            const int e = eg * 4 + i;                                          \
            _Float16 h0, l0, h1, l1;                                           \
            split16(va[i] * da, h0, l0);                                       \
            split16(vb[i] * db, h1, l1);                                       \
            h2 th = {h0, h1}, tl = {l0, l1};                                   \
            *(h2*)&B_l[buf][e * RS + 2 * kp]      = th;                        \
            *(h2*)&B_l[buf][e * RS + 32 + 2 * kp] = tl;                        \
        }                                                                      \
        if (sau < U) {                                                         \
            const float vr[4] = {raA.x, raA.y, raA.z, raA.w};                  \
            for (int j = 0; j < 2; ++j) {                                      \
                _Float16 h0, l0, h1, l1;                                       \
                split16(vr[2*j],   h0, l0);                                    \
                split16(vr[2*j+1], h1, l1);                                    \
                h2 th = {h0, h1}, tl = {l0, l1};                               \
                *(h2*)&A_l[buf][sau * RS + sak + 2*j]      = th;               \
                *(h2*)&A_l[buf][sau * RS + 32 + sak + 2*j] = tl;               \
            }                                                                  \
        }                                                                      \
    }

    __syncthreads();                    // zero-pad visible
    STAGE_LOAD(0);
    STAGE_WRITE(0, 0);
    __syncthreads();

    f4 acc[2][4];
    #pragma unroll
    for (int sr = 0; sr < 2; ++sr)
        #pragma unroll
        for (int sc = 0; sc < 4; ++sc)
            acc[sr][sc] = {0.f, 0.f, 0.f, 0.f};

    // ---- k-loop (double-buffered, one barrier per step) ----
    for (int kt = 0; kt < NKS; ++kt) {
        const int cur = kt & 1;

        // W2 row-sum loads (rows kt*32 + 2wv + {0,1}) — coalesced 1KB/instr
        float4 rw0 = ld4(&W2b[(size_t)(kt * 32 + 2 * wv)     * DD + lane * 4]);
        float4 rw1 = ld4(&W2b[(size_t)(kt * 32 + 2 * wv + 1) * DD + lane * 4]);

        if (kt + 1 < NKS) STAGE_LOAD(kt + 1);

        if (rg < NRT) {
            h8 ah[2], al[2];
            #pragma unroll
            for (int sr = 0; sr < 2; ++sr) {
                const int ao = (rg * 32 + sr * 16 + r16) * RS + g8;
                ah[sr] = *(const h8*)&A_l[cur][ao];
                al[sr] = *(const h8*)&A_l[cur][ao + 32];
            }
            #pragma unroll
            for (int sc = 0; sc < 4; ++sc) {
                const int bo = (cg * 64 + sc * 16 + r16) * RS + g8;
                h8 bh = *(const h8*)&B_l[cur][bo];
                h8 bl = *(const h8*)&B_l[cur][bo + 32];
                #pragma unroll
                for (int sr = 0; sr < 2; ++sr) {
                    acc[sr][sc] = __builtin_amdgcn_mfma_f32_16x16x32_f16(ah[sr], bh, acc[sr][sc], 0, 0, 0);
                    acc[sr][sc] = __builtin_amdgcn_mfma_f32_16x16x32_f16(al[sr], bh, acc[sr][sc], 0, 0, 0);
                    acc[sr][sc] = __builtin_amdgcn_mfma_f32_16x16x32_f16(ah[sr], bl, acc[sr][sc], 0, 0, 0);
                }
            }
        }

        // W2 reduce + write
        {
            float s0 = rw0.x + rw0.y + rw0.z + rw0.w;
            float s1 = rw1.x + rw1.y + rw1.z + rw1.w;
            #pragma unroll
            for (int m = 32; m >= 1; m >>= 1) {
                s0 += __shfl_xor(s0, m, 64);
                s1 += __shfl_xor(s1, m, 64);
            }
            if (lane == 0) {
                w2s_l[kt * 32 + 2 * wv]     = s0;
                w2s_l[kt * 32 + 2 * wv + 1] = s1;
            }
        }

        if (kt + 1 < NKS) STAGE_WRITE(cur ^ 1, kt + 1);
        __syncthreads();
    }
    #undef STAGE_LOAD
    #undef STAGE_WRITE

    // ---- epilogue: per row-tile, acc -> P (overlays B_l[0]) -> logits ----
    const int ug = tid >> 5;            // 0..31
    const int td = tid & 31;            // 0..31 (half-wave)
    float4 wrA = ld4(&w2s_l[td * 8]);
    float4 wrB = ld4(&w2s_l[td * 8 + 4]);

    for (int rt = 0; rt < 4; ++rt) {
        if (rt < NRT) {
            __syncthreads();
            if (rg == rt) {
                #pragma unroll
                for (int sr = 0; sr < 2; ++sr)
                    #pragma unroll
                    for (int sc = 0; sc < 4; ++sc)
                        #pragma unroll
                        for (int jj = 0; jj < 4; ++jj)
                            Pl[(sr*16 + (lane>>4)*4 + jj) * PS + cg*64 + sc*16 + r16] =
                                acc[sr][sc][jj];
            }
            __syncthreads();
            const int u = rt * 32 + ug;
            if (u < U) {
                int n = head_l[u];
                while (n >= 0) {
                    const float* bp = b1 + (size_t)n * DD;
                    float4 p0 = ld4(&Pl[ug * PS + td * 8]);
                    float4 p1 = ld4(&Pl[ug * PS + td * 8 + 4]);
                    float4 b0 = ld4(&bp[td * 8]);
                    float4 b1v = ld4(&bp[td * 8 + 4]);
                    float s = fmaxf(p0.x + b0.x,  0.f) * wrA.x
                            + fmaxf(p0.y + b0.y,  0.f) * wrA.y
                            + fmaxf(p0.z + b0.z,  0.f) * wrA.z
                            + fmaxf(p0.w + b0.w,  0.f) * wrA.w
                            + fmaxf(p1.x + b1v.x, 0.f) * wrB.x
                            + fmaxf(p1.y + b1v.y, 0.f) * wrB.y
                            + fmaxf(p1.z + b1v.z, 0.f) * wrB.z
                            + fmaxf(p1.w + b1v.w, 0.f) * wrB.w;
                    #pragma unroll
                    for (int m = 16; m >= 1; m >>= 1) s += __shfl_xor(s, m, 32);
                    if (td == 0) score_l[n] = s + b2s_l[n];
                    n = next_l[n];
                }
            }
        }
    }
    __syncthreads();

    // ---- softmax (exact f32, wave 0) ----
    if (tid < 64) {
        float l0 = score_l[tid], l1 = score_l[tid + 64];
        float M = fmaxf(l0, l1);
        #pragma unroll
        for (int m = 32; m >= 1; m >>= 1) M = fmaxf(M, __shfl_xor(M, m, 64));
        float e0 = expf(l0 - M), e1 = expf(l1 - M);
        float S = e0 + e1;
        #pragma unroll
        for (int m = 32; m >= 1; m >>= 1) S += __shfl_xor(S, m, 64);
        float inv = 1.f / S;
        score_l[tid]      = e0 * inv;
        score_l[tid + 64] = e1 * inv;
    }
    __syncthreads();

    // ---- sparse ent gather + x write ----
    if (tid < DD) {
        float w = 0.f;
        for (int n = 0; n < NN; ++n) {
            float s = score_l[n];
            if (s > 1e-9f)
                w = fmaf(s, ent_table[(size_t)tail_l[n] * DD + tid], w);
        }
        xbuf[(size_t)b * 512 + tid]       = w;
        xbuf[(size_t)b * 512 + 256 + tid] = d_l[tid];
    }
}

// ---------------------------------------------------------------------------
// batched linear
// ---------------------------------------------------------------------------
__global__ __launch_bounds__(256)
void gnn_lin(const float* __restrict__ lin_w,
             const float* __restrict__ lin_b,
             const float* __restrict__ xbuf,
             float* __restrict__ Y)
{
    __shared__ float x_l[LDRUGS * 512];

    const int g = blockIdx.x, tid = threadIdx.x;
    const int b0 = g * LDRUGS;

    #pragma unroll
    for (int i = 0; i < LDRUGS * 2; ++i) {
        int f = tid + i * 256;
        *reinterpret_cast<float4*>(&x_l[f * 4]) = ld4(&xbuf[(size_t)b0 * 512 + f * 4]);
    }
    __syncthreads();

    const float* lw = lin_w + (size_t)tid * 512;
    float dot[LDRUGS];
    #pragma unroll
    for (int d = 0; d < LDRUGS; ++d) dot[d] = 0.f;

    for (int k4 = 0; k4 < 128; ++k4) {
        float4 wv = ld4(&lw[k4 * 4]);
        #pragma unroll
        for (int d = 0; d < LDRUGS; ++d) {
            float4 xv = ld4(&x_l[d * 512 + k4 * 4]);
            dot[d] += wv.x * xv.x + wv.y * xv.y + wv.z * xv.z + wv.w * xv.w;
        }
    }

    const float bb = lin_b[tid];
    #pragma unroll
    for (int d = 0; d < LDRUGS; ++d) {
        if (b0 + d < NB)
            Y[(size_t)(b0 + d) * DD + tid] = fmaxf(dot[d] + bb, 0.f);
    }
}

// ---------------------------------------------------------------------------
// BN stats + apply
// ---------------------------------------------------------------------------
__global__ void bn_stats(const float* __restrict__ Y, float* __restrict__ stats)
{
    int d = blockIdx.x, t = threadIdx.x;
    float s = 0.f, ss = 0.f;
    for (int b = t; b < NB; b += 64) {
        float v = Y[(size_t)b * DD + d];
        s += v; ss += v * v;
    }
    #pragma unroll
    for (int m = 32; m >= 1; m >>= 1) {
        s  += __shfl_xor(s, m, 64);
        ss += __shfl_xor(ss, m, 64);
    }
    if (t == 0) {
        float mean = s * (1.f / NB);
        float var  = ss * (1.f / NB) - mean * mean;
        stats[d]      = mean;
        stats[DD + d] = rsqrtf(var + 1e-5f);
    }
}

__global__ void bn_apply(float* __restrict__ Y, const float* __restrict__ stats,
                         const float* __restrict__ gamma, const float* __restrict__ beta)
{
    int b = blockIdx.x, t = threadIdx.x;
    float mean = stats[t], inv = stats[DD + t];
    float v = Y[(size_t)b * DD + t];
    Y[(size_t)b * DD + t] = gamma[t] * (v - mean) * inv + beta[t];
}

extern "C" void kernel_launch(void* const* d_in, const int* in_sizes, int n_in,
                              void* d_out, int out_size, void* d_ws, size_t ws_size,
                              hipStream_t stream)
{
    const float* drug_table = (const float*)d_in[0];
    const float* rela_table = (const float*)d_in[1];
    const float* ent_table  = (const float*)d_in[2];
    const float* W1         = (const float*)d_in[3];
    const float* b1         = (const float*)d_in[4];
    const float* W2         = (const float*)d_in[5];
    const float* b2         = (const float*)d_in[6];
    const float* lin_w      = (const float*)d_in[7];
    const float* lin_b      = (const float*)d_in[8];
    const float* bn_g       = (const float*)d_in[9];
    const float* bn_b       = (const float*)d_in[10];
    const int*   drug_name  = (const int*)d_in[11];
    const int*   adj_tail   = (const int*)d_in[12];
    const int*   adj_rel    = (const int*)d_in[13];
    float* out = (float*)d_out;

    const int NBP = ((NB + LDRUGS - 1) / LDRUGS) * LDRUGS;   // 576
    float* b2s   = (float*)d_ws;                   // NN
    float* xbuf  = b2s + NN;                       // NBP*512
    float* stats = xbuf + (size_t)NBP * 512;       // 2*DD

    sum_b2<<<NN, 64, 0, stream>>>(b2, b2s);
    gnn_mm<<<NB, 1024, 0, stream>>>(drug_table, rela_table, ent_table,
                                    W1, b1, W2, drug_name, adj_tail, adj_rel,
                                    b2s, xbuf);
    gnn_lin<<<NBP / LDRUGS, 256, 0, stream>>>(lin_w, lin_b, xbuf, out);
    bn_stats<<<DD, 64, 0, stream>>>(out, stats);
    bn_apply<<<NB, DD, 0, stream>>>(out, stats, bn_g, bn_b);
}

// Round 10
// 134.272 us; speedup vs baseline: 3.6425x; 1.1577x over previous
//
#include <hip/hip_runtime.h>
#include <math.h>

#define DD   256   // feature dim
#define NN   128   // neighbors
#define NB   572   // drugs
#define NREL 100   // distinct relation rows
#define KS   32    // k-step (MFMA K)
#define NKS  (DD / KS)
#define EH   128   // e-half per mm block
#define RS   72    // LDS row stride in halves (8 slots x 8 halves + 8 pad)
#define PSS  132   // P scratch stride (f32)
#define LDRUGS 8

typedef _Float16 h8 __attribute__((ext_vector_type(8)));
typedef _Float16 h2 __attribute__((ext_vector_type(2)));
typedef float    f4 __attribute__((ext_vector_type(4)));

__device__ __forceinline__ float4 ld4(const float* p) {
    return *reinterpret_cast<const float4*>(p);
}
__device__ __forceinline__ void split16(float x, _Float16& hi, _Float16& lo) {
    hi = (_Float16)x;
    lo = (_Float16)(x - (float)hi);
}
// 8-slot swizzle: logical k-block blk (0..3), hilo (0/1), keyed on row bits
__device__ __forceinline__ int slot8(int blk, int row, int hilo) {
    return ((2 * blk + hilo + ((row >> 2) & 7)) & 7) * 8;
}

// ---------------------------------------------------------------------------
// Kernel 1: streaming row-sums. blocks 0..2NB-1: W2[b] half; block 2NB: b2.
// ---------------------------------------------------------------------------
__global__ __launch_bounds__(256)
void sum_rows(const float* __restrict__ W2, const float* __restrict__ b2,
              float* __restrict__ w2s, float* __restrict__ b2s)
{
    const int blk  = blockIdx.x;
    const int tid  = threadIdx.x;
    const int lane = tid & 63;
    const int wv   = tid >> 6;

    if (blk < 2 * NB) {
        const int b = blk >> 1, half = blk & 1;
        const float* src = W2 + (size_t)b * DD * DD + (size_t)half * (DD / 2) * DD;
        float* dst = w2s + (size_t)b * DD + half * (DD / 2);
        for (int r = wv; r < DD / 2; r += 4) {
            float4 v = ld4(&src[r * DD + lane * 4]);
            float s = v.x + v.y + v.z + v.w;
            #pragma unroll
            for (int m = 32; m >= 1; m >>= 1) s += __shfl_xor(s, m, 64);
            if (lane == 0) dst[r] = s;
        }
    } else {
        for (int r = wv; r < NN; r += 4) {
            float4 v = ld4(&b2[r * DD + lane * 4]);
            float s = v.x + v.y + v.z + v.w;
            #pragma unroll
            for (int m = 32; m >= 1; m >>= 1) s += __shfl_xor(s, m, 64);
            if (lane == 0) b2s[r] = s;
        }
    }
}

// ---------------------------------------------------------------------------
// Kernel 2: MFMA matmul + partial logits. Block = (drug b, e-half h).
// 512 threads / 8 waves (2 row-groups x 4 col-groups of 32 e each).
// f16 hi/lo 3-product; single-buffered swizzled LDS; 2 barriers per k-step.
// part[b, h*128+n] = sum_{e in half} relu(P[u(n),e] + b1[n,e]) * w2s[b,e]
// ---------------------------------------------------------------------------
__global__ __launch_bounds__(512, 4)
void gnn_mm(const float* __restrict__ drug_table,
            const float* __restrict__ rela_table,
            const float* __restrict__ W1,
            const float* __restrict__ b1,
            const int*   __restrict__ drug_name,
            const int*   __restrict__ adj_relation,
            const float* __restrict__ w2s_g,
            float* __restrict__ part)
{
    __shared__ __align__(16) _Float16 AB_l[2 * 128 * RS];  // A | B, 36.9 KB
    __shared__ float d_l[DD];
    __shared__ float w2s_l[EH];
    __shared__ int   rel_l[NN], urel_l[NN], head_l[NN], next_l[NN];
    __shared__ int   map_l[NREL];
    __shared__ int   U_l, c0_l;

    _Float16* A_l = AB_l;
    _Float16* B_l = AB_l + 128 * RS;
    float*    Pl  = reinterpret_cast<float*>(AB_l);   // 32 x 132 f32 overlay

    const int bid  = blockIdx.x;
    const int b    = bid >> 1, h = bid & 1;
    const int tid  = threadIdx.x;
    const int lane = tid & 63;
    const int wv   = tid >> 6;          // 0..7
    const int rg   = wv >> 2;           // 0..1
    const int cg   = wv & 3;            // 0..3 (32 e each)
    const int r16  = lane & 15;
    const int gb   = lane >> 4;         // k-block 0..3

    // ---- setup ----
    if (tid < NN) { rel_l[tid] = adj_relation[b * NN + tid]; head_l[tid] = -1; }
    if (tid < NREL) map_l[tid] = -1;
    if (tid < DD)  d_l[tid] = drug_table[(size_t)drug_name[b] * DD + tid];
    if (tid >= DD && tid < DD + EH)
        w2s_l[tid - DD] = w2s_g[(size_t)b * DD + h * EH + (tid - DD)];
    __syncthreads();
    if (tid < NN) map_l[rel_l[tid]] = 1;
    __syncthreads();

    // ---- ballot compaction of <=100 marked relations ----
    bool mk = false; int rank = 0, tot = 0;
    if (tid < 128) {
        mk = (tid < NREL) && (map_l[tid] != -1);
        unsigned long long bal = __ballot(mk);
        rank = __popcll(bal & ((1ull << (tid & 63)) - 1));
        tot  = __popcll(bal);
    }
    if (tid < 64) {
        if (mk) { map_l[tid] = rank; urel_l[rank] = tid; }
        if (tid == 0) c0_l = tot;
    }
    __syncthreads();
    if (tid >= 64 && tid < 128) {
        const int base = c0_l;
        if (mk) { map_l[tid] = base + rank; urel_l[base + rank] = tid; }
        if (tid == 64) U_l = base + tot;
    }
    __syncthreads();
    if (tid < NN)
        next_l[tid] = atomicExch(&head_l[map_l[rel_l[tid]]], tid);
    __syncthreads();

    const int U   = U_l;
    const int NRT = (U + 31) >> 5;

    const float* W1b = W1 + (size_t)b * DD * DD;

    // ---- zero-pad A rows U..NRT*32-1 (all 64 data halves) ----
    {
        const int padrows = NRT * 32 - U;
        h2 z = {(_Float16)0.f, (_Float16)0.f};
        for (int x = tid; x < padrows * 32; x += 512) {
            int r = U + (x >> 5), m = (x & 31) * 2;
            *(h2*)&A_l[r * RS + m] = z;
        }
    }

    // staging maps
    const int kp  = tid >> 5;           // B: k-pair 0..15
    const int el  = tid & 31;           // B: e-quad 0..31
    const int sau = tid >> 2;           // A: u row 0..127
    const int sab = tid & 3;            // A: k-octet 0..3

    float4 rbA, rbB, raA, raB;

    #define STAGE_LOAD(kt_) {                                                  \
        const int k0_ = (kt_) * KS;                                            \
        rbA = ld4(&W1b[(size_t)(k0_ + 2 * kp) * DD + h * EH + el * 4]);        \
        rbB = ld4(&W1b[(size_t)(k0_ + 2 * kp + 1) * DD + h * EH + el * 4]);    \
        if (sau < U) {                                                         \
            const float* rr = rela_table + (size_t)urel_l[sau] * DD + k0_ + sab * 8;\
            raA = ld4(rr); raB = ld4(rr + 4);                                  \
        }                                                                      \
    }

    #define STAGE_WRITE(kt_) {                                                 \
        const int k0_ = (kt_) * KS;                                            \
        const float da = d_l[k0_ + 2 * kp], db = d_l[k0_ + 2 * kp + 1];        \
        const float va[4] = {rbA.x, rbA.y, rbA.z, rbA.w};                      \
        const float vb[4] = {rbB.x, rbB.y, rbB.z, rbB.w};                      \
        const int wo = (2 * kp) & 7, bk = kp >> 2;                             \
        for (int i = 0; i < 4; ++i) {                                          \
            const int e = el * 4 + i;                                          \
            _Float16 h0, l0, h1, l1;                                           \
            split16(va[i] * da, h0, l0);                                       \
            split16(vb[i] * db, h1, l1);                                       \
            h2 th = {h0, h1}, tl = {l0, l1};                                   \
            *(h2*)&B_l[e * RS + slot8(bk, e, 0) + wo] = th;                    \
            *(h2*)&B_l[e * RS + slot8(bk, e, 1) + wo] = tl;                    \
        }                                                                      \
        if (sau < U) {                                                         \
            const float vr[8] = {raA.x, raA.y, raA.z, raA.w,                   \
                                 raB.x, raB.y, raB.z, raB.w};                  \
            h8 hv, lv;                                                         \
            for (int j = 0; j < 8; ++j) {                                      \
                _Float16 hh, ll;                                               \
                split16(vr[j], hh, ll);                                        \
                hv[j] = hh; lv[j] = ll;                                        \
            }                                                                  \
            *(h8*)&A_l[sau * RS + slot8(sab, sau, 0)] = hv;                    \
            *(h8*)&A_l[sau * RS + slot8(sab, sau, 1)] = lv;                    \
        }                                                                      \
    }

    STAGE_LOAD(0);
    STAGE_WRITE(0);
    __syncthreads();

    f4 acc[2][2][2];   // [p][sr][sc]
    #pragma unroll
    for (int p = 0; p < 2; ++p)
        #pragma unroll
        for (int sr = 0; sr < 2; ++sr)
            #pragma unroll
            for (int sc = 0; sc < 2; ++sc)
                acc[p][sr][sc] = {0.f, 0.f, 0.f, 0.f};

    // ---- k-loop: single buffer, loads issued early (T14) ----
    for (int kt = 0; kt < NKS; ++kt) {
        if (kt + 1 < NKS) STAGE_LOAD(kt + 1);

        h8 bh[2], bl[2];
        #pragma unroll
        for (int sc = 0; sc < 2; ++sc) {
            const int e = cg * 32 + sc * 16 + r16;
            bh[sc] = *(const h8*)&B_l[e * RS + slot8(gb, e, 0)];
            bl[sc] = *(const h8*)&B_l[e * RS + slot8(gb, e, 1)];
        }
        #pragma unroll
        for (int p = 0; p < 2; ++p) {
            const int rt = rg + 2 * p;
            if (rt < NRT) {
                #pragma unroll
                for (int sr = 0; sr < 2; ++sr) {
                    const int row = rt * 32 + sr * 16 + r16;
                    h8 ah = *(const h8*)&A_l[row * RS + slot8(gb, row, 0)];
                    h8 al = *(const h8*)&A_l[row * RS + slot8(gb, row, 1)];
                    #pragma unroll
                    for (int sc = 0; sc < 2; ++sc) {
                        acc[p][sr][sc] = __builtin_amdgcn_mfma_f32_16x16x32_f16(ah, bh[sc], acc[p][sr][sc], 0, 0, 0);
                        acc[p][sr][sc] = __builtin_amdgcn_mfma_f32_16x16x32_f16(al, bh[sc], acc[p][sr][sc], 0, 0, 0);
                        acc[p][sr][sc] = __builtin_amdgcn_mfma_f32_16x16x32_f16(ah, bl[sc], acc[p][sr][sc], 0, 0, 0);
                    }
                }
            }
        }
        __syncthreads();                 // all reads of tile kt done
        if (kt + 1 < NKS) STAGE_WRITE(kt + 1);
        __syncthreads();                 // tile kt+1 visible
    }
    #undef STAGE_LOAD
    #undef STAGE_WRITE

    // ---- epilogue: per row-tile, acc -> P (overlays arena) -> partial logits
    const int ug   = tid >> 4;          // 0..31
    const int td16 = tid & 15;
    float4 w0 = ld4(&w2s_l[td16 * 8]);
    float4 w1v = ld4(&w2s_l[td16 * 8 + 4]);

    for (int rt = 0; rt < 4; ++rt) {
        if (rt < NRT) {
            __syncthreads();
            if ((rt & 1) == rg) {
                const int p = rt >> 1;
                #pragma unroll
                for (int sr = 0; sr < 2; ++sr)
                    #pragma unroll
                    for (int sc = 0; sc < 2; ++sc)
                        #pragma unroll
                        for (int jj = 0; jj < 4; ++jj)
                            Pl[(sr * 16 + gb * 4 + jj) * PSS + cg * 32 + sc * 16 + r16] =
                                acc[p][sr][sc][jj];
            }
            __syncthreads();
            const int u = rt * 32 + ug;
            if (u < U) {
                float4 p0 = ld4(&Pl[ug * PSS + td16 * 8]);
                float4 p1 = ld4(&Pl[ug * PSS + td16 * 8 + 4]);
                int n = head_l[u];
                while (n >= 0) {
                    const float* bp = b1 + (size_t)n * DD + h * EH + td16 * 8;
                    float4 b0 = ld4(bp);
                    float4 b1v = ld4(bp + 4);
                    float s = fmaxf(p0.x + b0.x,  0.f) * w0.x
                            + fmaxf(p0.y + b0.y,  0.f) * w0.y
                            + fmaxf(p0.z + b0.z,  0.f) * w0.z
                            + fmaxf(p0.w + b0.w,  0.f) * w0.w
                            + fmaxf(p1.x + b1v.x, 0.f) * w1v.x
                            + fmaxf(p1.y + b1v.y, 0.f) * w1v.y
                            + fmaxf(p1.z + b1v.z, 0.f) * w1v.z
                            + fmaxf(p1.w + b1v.w, 0.f) * w1v.w;
                    #pragma unroll
                    for (int m = 8; m >= 1; m >>= 1) s += __shfl_xor(s, m, 16);
                    if (td16 == 0) part[(size_t)b * 256 + h * NN + n] = s;
                    n = next_l[n];
                }
            }
        }
    }
}

// ---------------------------------------------------------------------------
// Kernel 3: per drug — combine partials, softmax, sparse ent gather, x->xbuf
// ---------------------------------------------------------------------------
__global__ __launch_bounds__(256)
void gnn_gather(const float* __restrict__ drug_table,
                const float* __restrict__ ent_table,
                const int*   __restrict__ drug_name,
                const int*   __restrict__ adj_tail,
                const float* __restrict__ part,
                const float* __restrict__ b2s_g,
                float* __restrict__ xbuf)
{
    __shared__ float score_l[NN];
    __shared__ int   tail_l[NN];

    const int b = blockIdx.x, tid = threadIdx.x;

    if (tid < NN) {
        tail_l[tid]  = adj_tail[b * NN + tid];
        score_l[tid] = part[(size_t)b * 256 + tid]
                     + part[(size_t)b * 256 + NN + tid] + b2s_g[tid];
    }
    __syncthreads();

    if (tid < 64) {
        float l0 = score_l[tid], l1 = score_l[tid + 64];
        float M = fmaxf(l0, l1);
        #pragma unroll
        for (int m = 32; m >= 1; m >>= 1) M = fmaxf(M, __shfl_xor(M, m, 64));
        float e0 = expf(l0 - M), e1 = expf(l1 - M);
        float S = e0 + e1;
        #pragma unroll
        for (int m = 32; m >= 1; m >>= 1) S += __shfl_xor(S, m, 64);
        float inv = 1.f / S;
        score_l[tid]      = e0 * inv;
        score_l[tid + 64] = e1 * inv;
    }
    __syncthreads();

    // sparse gather (softmax ~one-hot; skipped mass < 1.3e-7)
    float w = 0.f;
    for (int n = 0; n < NN; ++n) {
        float s = score_l[n];
        if (s > 1e-9f)
            w = fmaf(s, ent_table[(size_t)tail_l[n] * DD + tid], w);
    }
    xbuf[(size_t)b * 512 + tid]       = w;
    xbuf[(size_t)b * 512 + 256 + tid] = drug_table[(size_t)drug_name[b] * DD + tid];
}

// ---------------------------------------------------------------------------
// Kernel 4: batched linear
// ---------------------------------------------------------------------------
__global__ __launch_bounds__(256)
void gnn_lin(const float* __restrict__ lin_w,
             const float* __restrict__ lin_b,
             const float* __restrict__ xbuf,
             float* __restrict__ Y)
{
    __shared__ float x_l[LDRUGS * 512];

    const int g = blockIdx.x, tid = threadIdx.x;
    const int b0 = g * LDRUGS;

    #pragma unroll
    for (int i = 0; i < LDRUGS * 2; ++i) {
        int f = tid + i * 256;
        *reinterpret_cast<float4*>(&x_l[f * 4]) = ld4(&xbuf[(size_t)b0 * 512 + f * 4]);
    }
    __syncthreads();

    const float* lw = lin_w + (size_t)tid * 512;
    float dot[LDRUGS];
    #pragma unroll
    for (int d = 0; d < LDRUGS; ++d) dot[d] = 0.f;

    for (int k4 = 0; k4 < 128; ++k4) {
        float4 wv = ld4(&lw[k4 * 4]);
        #pragma unroll
        for (int d = 0; d < LDRUGS; ++d) {
            float4 xv = ld4(&x_l[d * 512 + k4 * 4]);
            dot[d] += wv.x * xv.x + wv.y * xv.y + wv.z * xv.z + wv.w * xv.w;
        }
    }

    const float bb = lin_b[tid];
    #pragma unroll
    for (int d = 0; d < LDRUGS; ++d) {
        if (b0 + d < NB)
            Y[(size_t)(b0 + d) * DD + tid] = fmaxf(dot[d] + bb, 0.f);
    }
}

// ---------------------------------------------------------------------------
// BN stats + apply
// ---------------------------------------------------------------------------
__global__ void bn_stats(const float* __restrict__ Y, float* __restrict__ stats)
{
    int d = blockIdx.x, t = threadIdx.x;
    float s = 0.f, ss = 0.f;
    for (int b = t; b < NB; b += 64) {
        float v = Y[(size_t)b * DD + d];
        s += v; ss += v * v;
    }
    #pragma unroll
    for (int m = 32; m >= 1; m >>= 1) {
        s  += __shfl_xor(s, m, 64);
        ss += __shfl_xor(ss, m, 64);
    }
    if (t == 0) {
        float mean = s * (1.f / NB);
        float var  = ss * (1.f / NB) - mean * mean;
        stats[d]      = mean;
        stats[DD + d] = rsqrtf(var + 1e-5f);
    }
}

__global__ void bn_apply(float* __restrict__ Y, const float* __restrict__ stats,
                         const float* __restrict__ gamma, const float* __restrict__ beta)
{
    int b = blockIdx.x, t = threadIdx.x;
    float mean = stats[t], inv = stats[DD + t];
    float v = Y[(size_t)b * DD + t];
    Y[(size_t)b * DD + t] = gamma[t] * (v - mean) * inv + beta[t];
}

extern "C" void kernel_launch(void* const* d_in, const int* in_sizes, int n_in,
                              void* d_out, int out_size, void* d_ws, size_t ws_size,
                              hipStream_t stream)
{
    const float* drug_table = (const float*)d_in[0];
    const float* rela_table = (const float*)d_in[1];
    const float* ent_table  = (const float*)d_in[2];
    const float* W1         = (const float*)d_in[3];
    const float* b1         = (const float*)d_in[4];
    const float* W2         = (const float*)d_in[5];
    const float* b2         = (const float*)d_in[6];
    const float* lin_w      = (const float*)d_in[7];
    const float* lin_b      = (const float*)d_in[8];
    const float* bn_g       = (const float*)d_in[9];
    const float* bn_b       = (const float*)d_in[10];
    const int*   drug_name  = (const int*)d_in[11];
    const int*   adj_tail   = (const int*)d_in[12];
    const int*   adj_rel    = (const int*)d_in[13];
    float* out = (float*)d_out;

    const int NBP = ((NB + LDRUGS - 1) / LDRUGS) * LDRUGS;   // 576
    float* w2s   = (float*)d_ws;                   // NB*DD
    float* b2s   = w2s + (size_t)NB * DD;          // NN
    float* part  = b2s + NN;                       // NB*256
    float* xbuf  = part + (size_t)NB * 256;        // NBP*512
    float* stats = xbuf + (size_t)NBP * 512;       // 2*DD

    sum_rows<<<2 * NB + 1, 256, 0, stream>>>(W2, b2, w2s, b2s);
    gnn_mm<<<2 * NB, 512, 0, stream>>>(drug_table, rela_table, W1, b1,
                                       drug_name, adj_rel, w2s, part);
    gnn_gather<<<NB, 256, 0, stream>>>(drug_table, ent_table, drug_name,
                                       adj_tail, part, b2s, xbuf);
    gnn_lin<<<NBP / LDRUGS, 256, 0, stream>>>(lin_w, lin_b, xbuf, out);
    bn_stats<<<DD, 64, 0, stream>>>(out, stats);
    bn_apply<<<NB, DD, 0, stream>>>(out, stats, bn_g, bn_b);
}

// Round 11
// 130.381 us; speedup vs baseline: 3.7512x; 1.0298x over previous
//
#include <hip/hip_runtime.h>
#include <math.h>

#define DD   256   // feature dim
#define NN   128   // neighbors
#define NB   572   // drugs
#define NREL 100   // distinct relation rows
#define KS   32    // k-step (MFMA K)
#define NKS  (DD / KS)
#define EH   128   // e-half per mm block
#define RS   80    // LDS row stride in halves (160B, 40 words == 8 mod 32)
#define PSS  132   // P scratch stride (f32)
#define LDRUGS 8

typedef _Float16 h8 __attribute__((ext_vector_type(8)));
typedef _Float16 h2 __attribute__((ext_vector_type(2)));
typedef float    f4 __attribute__((ext_vector_type(4)));

__device__ __forceinline__ float4 ld4(const float* p) {
    return *reinterpret_cast<const float4*>(p);
}
__device__ __forceinline__ void split16(float x, _Float16& hi, _Float16& lo) {
    hi = (_Float16)x;
    lo = (_Float16)(x - (float)hi);
}
// XOR slot swizzle: blk2 = 2*k_octet + hilo (0..7); returns halves offset
__device__ __forceinline__ int slotx(int blk2, int row) {
    return ((blk2 ^ (row & 7)) & 7) * 8;
}

// ---------------------------------------------------------------------------
// Kernel 0: b2 row-sums (tiny)
// ---------------------------------------------------------------------------
__global__ void sum_b2(const float* __restrict__ b2, float* __restrict__ b2s)
{
    const int n = blockIdx.x, t = threadIdx.x;   // 128 x 64
    float4 v = ld4(&b2[n * DD + t * 4]);
    float s = v.x + v.y + v.z + v.w;
    #pragma unroll
    for (int m = 32; m >= 1; m >>= 1) s += __shfl_xor(s, m, 64);
    if (t == 0) b2s[n] = s;
}

// ---------------------------------------------------------------------------
// Kernel 1: MFMA matmul + fused W2 row-sums + partial logits.
// Block = (drug b, e-half h). 512 threads / 8 waves (2 rg x 4 cg).
// f16 hi/lo 3-product; single-buffer XOR-swizzled LDS (stride 80 halves);
// W2 row-half summed 16 rows per k-step, hidden under MFMA.
// part[b, h*128+n] = sum_{e in half} relu(P[u(n),e] + b1[n,e]) * w2s[e]
// ---------------------------------------------------------------------------
__global__ __launch_bounds__(512, 4)
void gnn_mm(const float* __restrict__ drug_table,
            const float* __restrict__ rela_table,
            const float* __restrict__ W1,
            const float* __restrict__ b1,
            const float* __restrict__ W2,
            const int*   __restrict__ drug_name,
            const int*   __restrict__ adj_relation,
            float* __restrict__ part)
{
    __shared__ __align__(16) _Float16 AB_l[2 * 128 * RS];  // A | B, 40 KB
    __shared__ float d_l[DD];
    __shared__ float w2s_l[EH];
    __shared__ int   rel_l[NN], urel_l[NN], head_l[NN], next_l[NN];
    __shared__ int   map_l[NREL];
    __shared__ int   U_l, c0_l;

    _Float16* A_l = AB_l;
    _Float16* B_l = AB_l + 128 * RS;
    float*    Pl  = reinterpret_cast<float*>(AB_l);   // 32 x 132 f32 overlay

    const int bid  = blockIdx.x;
    const int b    = bid >> 1, h = bid & 1;
    const int tid  = threadIdx.x;
    const int lane = tid & 63;
    const int wv   = tid >> 6;          // 0..7
    const int rg   = wv >> 2;           // 0..1
    const int cg   = wv & 3;            // 0..3 (32 e each)
    const int r16  = lane & 15;
    const int gb   = lane >> 4;         // k-octet 0..3

    // ---- setup ----
    if (tid < NN) { rel_l[tid] = adj_relation[b * NN + tid]; head_l[tid] = -1; }
    if (tid < NREL) map_l[tid] = -1;
    if (tid < DD)  d_l[tid] = drug_table[(size_t)drug_name[b] * DD + tid];
    __syncthreads();
    if (tid < NN) map_l[rel_l[tid]] = 1;
    __syncthreads();

    // ---- ballot compaction of <=100 marked relations ----
    bool mk = false; int rank = 0, tot = 0;
    if (tid < 128) {
        mk = (tid < NREL) && (map_l[tid] != -1);
        unsigned long long bal = __ballot(mk);
        rank = __popcll(bal & ((1ull << (tid & 63)) - 1));
        tot  = __popcll(bal);
    }
    if (tid < 64) {
        if (mk) { map_l[tid] = rank; urel_l[rank] = tid; }
        if (tid == 0) c0_l = tot;
    }
    __syncthreads();
    if (tid >= 64 && tid < 128) {
        const int base = c0_l;
        if (mk) { map_l[tid] = base + rank; urel_l[base + rank] = tid; }
        if (tid == 64) U_l = base + tot;
    }
    __syncthreads();
    if (tid < NN)
        next_l[tid] = atomicExch(&head_l[map_l[rel_l[tid]]], tid);
    __syncthreads();

    const int U   = U_l;
    const int NRT = (U + 31) >> 5;

    const float* W1b = W1 + (size_t)b * DD * DD;
    const float* W2b = W2 + (size_t)b * DD * DD;

    // ---- zero-pad A rows U..NRT*32-1 (data halves [0,64)) ----
    {
        const int padrows = NRT * 32 - U;
        h8 z = {(_Float16)0.f,(_Float16)0.f,(_Float16)0.f,(_Float16)0.f,
                (_Float16)0.f,(_Float16)0.f,(_Float16)0.f,(_Float16)0.f};
        for (int x = tid; x < padrows * 8; x += 512) {
            int r = U + (x >> 3), c = (x & 7) * 8;
            *(h8*)&A_l[r * RS + c] = z;
        }
    }

    // staging maps
    const int kp  = tid >> 5;           // B: k-pair 0..15
    const int el  = tid & 31;           // B: e lane
    const int sau = tid >> 2;           // A: u row 0..127
    const int sab = tid & 3;            // A: k-octet 0..3

    float rb0[4], rb1[4];
    float4 raA, raB;

    #define STAGE_LOAD(kt_) {                                                  \
        const int k0_ = (kt_) * KS;                                            \
        const float* w1p0 = &W1b[(size_t)(k0_ + 2 * kp) * DD + h * EH + el];   \
        const float* w1p1 = w1p0 + DD;                                         \
        _Pragma("unroll")                                                      \
        for (int i = 0; i < 4; ++i) {                                          \
            rb0[i] = w1p0[32 * i];                                             \
            rb1[i] = w1p1[32 * i];                                             \
        }                                                                      \
        if (sau < U) {                                                         \
            const float* rr = rela_table + (size_t)urel_l[sau] * DD + k0_ + sab * 8;\
            raA = ld4(rr); raB = ld4(rr + 4);                                  \
        }                                                                      \
    }

    #define STAGE_WRITE(kt_) {                                                 \
        const int k0_ = (kt_) * KS;                                            \
        const float da = d_l[k0_ + 2 * kp], db = d_l[k0_ + 2 * kp + 1];        \
        const int bk2 = 2 * (kp >> 2);                                         \
        const int wo  = (2 * kp) & 7;                                          \
        _Pragma("unroll")                                                      \
        for (int i = 0; i < 4; ++i) {                                          \
            const int e = el + 32 * i;                                         \
            _Float16 h0, l0, h1, l1;                                           \
            split16(rb0[i] * da, h0, l0);                                      \
            split16(rb1[i] * db, h1, l1);                                      \
            h2 th = {h0, h1}, tl = {l0, l1};                                   \
            *(h2*)&B_l[e * RS + slotx(bk2,     e) + wo] = th;                  \
            *(h2*)&B_l[e * RS + slotx(bk2 + 1, e) + wo] = tl;                  \
        }                                                                      \
        if (sau < U) {                                                         \
            const float vr[8] = {raA.x, raA.y, raA.z, raA.w,                   \
                                 raB.x, raB.y, raB.z, raB.w};                  \
            h8 hv, lv;                                                         \
            _Pragma("unroll")                                                  \
            for (int j = 0; j < 8; ++j) {                                      \
                _Float16 hh, ll;                                               \
                split16(vr[j], hh, ll);                                        \
                hv[j] = hh; lv[j] = ll;                                        \
            }                                                                  \
            *(h8*)&A_l[sau * RS + slotx(2 * sab,     sau)] = hv;               \
            *(h8*)&A_l[sau * RS + slotx(2 * sab + 1, sau)] = lv;               \
        }                                                                      \
    }

    STAGE_LOAD(0);
    STAGE_WRITE(0);
    __syncthreads();

    f4 acc[2][2][2];   // [p][sr][sc]
    #pragma unroll
    for (int p = 0; p < 2; ++p)
        #pragma unroll
        for (int sr = 0; sr < 2; ++sr)
            #pragma unroll
            for (int sc = 0; sc < 2; ++sc)
                acc[p][sr][sc] = {0.f, 0.f, 0.f, 0.f};

    // ---- k-loop ----
    for (int kt = 0; kt < NKS; ++kt) {
        if (kt + 1 < NKS) STAGE_LOAD(kt + 1);

        // fused W2 row-sum loads: local rows kt*16 + 2wv + {0,1}
        float4 rw0 = ld4(&W2b[(size_t)(h * EH + kt * 16 + 2 * wv)     * DD + lane * 4]);
        float4 rw1 = ld4(&W2b[(size_t)(h * EH + kt * 16 + 2 * wv + 1) * DD + lane * 4]);

        h8 bh[2], bl[2];
        #pragma unroll
        for (int sc = 0; sc < 2; ++sc) {
            const int e = cg * 32 + sc * 16 + r16;
            bh[sc] = *(const h8*)&B_l[e * RS + slotx(2 * gb,     e)];
            bl[sc] = *(const h8*)&B_l[e * RS + slotx(2 * gb + 1, e)];
        }
        #pragma unroll
        for (int p = 0; p < 2; ++p) {
            const int rt = rg + 2 * p;
            if (rt < NRT) {
                #pragma unroll
                for (int sr = 0; sr < 2; ++sr) {
                    const int row = rt * 32 + sr * 16 + r16;
                    h8 ah = *(const h8*)&A_l[row * RS + slotx(2 * gb,     row)];
                    h8 al = *(const h8*)&A_l[row * RS + slotx(2 * gb + 1, row)];
                    #pragma unroll
                    for (int sc = 0; sc < 2; ++sc) {
                        acc[p][sr][sc] = __builtin_amdgcn_mfma_f32_16x16x32_f16(ah, bh[sc], acc[p][sr][sc], 0, 0, 0);
                        acc[p][sr][sc] = __builtin_amdgcn_mfma_f32_16x16x32_f16(al, bh[sc], acc[p][sr][sc], 0, 0, 0);
                        acc[p][sr][sc] = __builtin_amdgcn_mfma_f32_16x16x32_f16(ah, bl[sc], acc[p][sr][sc], 0, 0, 0);
                    }
                }
            }
        }

        // W2 reduce (latency hidden under MFMA above)
        {
            float s0 = rw0.x + rw0.y + rw0.z + rw0.w;
            float s1 = rw1.x + rw1.y + rw1.z + rw1.w;
            #pragma unroll
            for (int m = 32; m >= 1; m >>= 1) {
                s0 += __shfl_xor(s0, m, 64);
                s1 += __shfl_xor(s1, m, 64);
            }
            if (lane == 0) {
                w2s_l[kt * 16 + 2 * wv]     = s0;
                w2s_l[kt * 16 + 2 * wv + 1] = s1;
            }
        }

        __syncthreads();                 // all reads of tile kt done
        if (kt + 1 < NKS) STAGE_WRITE(kt + 1);
        __syncthreads();                 // tile kt+1 visible
    }
    #undef STAGE_LOAD
    #undef STAGE_WRITE

    // ---- epilogue: per row-tile, acc -> P (overlays arena) -> partial logits
    const int ug   = tid >> 4;          // 0..31
    const int td16 = tid & 15;
    float4 w0 = ld4(&w2s_l[td16 * 8]);
    float4 w1v = ld4(&w2s_l[td16 * 8 + 4]);

    for (int rt = 0; rt < 4; ++rt) {
        if (rt < NRT) {
            __syncthreads();
            if ((rt & 1) == rg) {
                const int p = rt >> 1;
                #pragma unroll
                for (int sr = 0; sr < 2; ++sr)
                    #pragma unroll
                    for (int sc = 0; sc < 2; ++sc)
                        #pragma unroll
                        for (int jj = 0; jj < 4; ++jj)
                            Pl[(sr * 16 + gb * 4 + jj) * PSS + cg * 32 + sc * 16 + r16] =
                                acc[p][sr][sc][jj];
            }
            __syncthreads();
            const int u = rt * 32 + ug;
            if (u < U) {
                float4 p0 = ld4(&Pl[ug * PSS + td16 * 8]);
                float4 p1 = ld4(&Pl[ug * PSS + td16 * 8 + 4]);
                int n = head_l[u];
                while (n >= 0) {
                    const float* bp = b1 + (size_t)n * DD + h * EH + td16 * 8;
                    float4 b0 = ld4(bp);
                    float4 b1v = ld4(bp + 4);
                    float s = fmaxf(p0.x + b0.x,  0.f) * w0.x
                            + fmaxf(p0.y + b0.y,  0.f) * w0.y
                            + fmaxf(p0.z + b0.z,  0.f) * w0.z
                            + fmaxf(p0.w + b0.w,  0.f) * w0.w
                            + fmaxf(p1.x + b1v.x, 0.f) * w1v.x
                            + fmaxf(p1.y + b1v.y, 0.f) * w1v.y
                            + fmaxf(p1.z + b1v.z, 0.f) * w1v.z
                            + fmaxf(p1.w + b1v.w, 0.f) * w1v.w;
                    #pragma unroll
                    for (int m = 8; m >= 1; m >>= 1) s += __shfl_xor(s, m, 16);
                    if (td16 == 0) part[(size_t)b * 256 + h * NN + n] = s;
                    n = next_l[n];
                }
            }
        }
    }
}

// ---------------------------------------------------------------------------
// Kernel 2: per drug — combine partials (+b2s), softmax, sparse ent gather
// ---------------------------------------------------------------------------
__global__ __launch_bounds__(256)
void gnn_gather(const float* __restrict__ drug_table,
                const float* __restrict__ ent_table,
                const int*   __restrict__ drug_name,
                const int*   __restrict__ adj_tail,
                const float* __restrict__ part,
                const float* __restrict__ b2s_g,
                float* __restrict__ xbuf)
{
    __shared__ float score_l[NN];
    __shared__ int   tail_l[NN];

    const int b = blockIdx.x, tid = threadIdx.x;

    if (tid < NN) {
        tail_l[tid]  = adj_tail[b * NN + tid];
        score_l[tid] = part[(size_t)b * 256 + tid]
                     + part[(size_t)b * 256 + NN + tid] + b2s_g[tid];
    }
    __syncthreads();

    if (tid < 64) {
        float l0 = score_l[tid], l1 = score_l[tid + 64];
        float M = fmaxf(l0, l1);
        #pragma unroll
        for (int m = 32; m >= 1; m >>= 1) M = fmaxf(M, __shfl_xor(M, m, 64));
        float e0 = expf(l0 - M), e1 = expf(l1 - M);
        float S = e0 + e1;
        #pragma unroll
        for (int m = 32; m >= 1; m >>= 1) S += __shfl_xor(S, m, 64);
        float inv = 1.f / S;
        score_l[tid]      = e0 * inv;
        score_l[tid + 64] = e1 * inv;
    }
    __syncthreads();

    // sparse gather (softmax ~one-hot; skipped mass < 1.3e-7)
    float w = 0.f;
    for (int n = 0; n < NN; ++n) {
        float s = score_l[n];
        if (s > 1e-9f)
            w = fmaf(s, ent_table[(size_t)tail_l[n] * DD + tid], w);
    }
    xbuf[(size_t)b * 512 + tid]       = w;
    xbuf[(size_t)b * 512 + 256 + tid] = drug_table[(size_t)drug_name[b] * DD + tid];
}

// ---------------------------------------------------------------------------
// Kernel 3: batched linear
// ---------------------------------------------------------------------------
__global__ __launch_bounds__(256)
void gnn_lin(const float* __restrict__ lin_w,
             const float* __restrict__ lin_b,
             const float* __restrict__ xbuf,
             float* __restrict__ Y)
{
    __shared__ float x_l[LDRUGS * 512];

    const int g = blockIdx.x, tid = threadIdx.x;
    const int b0 = g * LDRUGS;

    #pragma unroll
    for (int i = 0; i < LDRUGS * 2; ++i) {
        int f = tid + i * 256;
        *reinterpret_cast<float4*>(&x_l[f * 4]) = ld4(&xbuf[(size_t)b0 * 512 + f * 4]);
    }
    __syncthreads();

    const float* lw = lin_w + (size_t)tid * 512;
    float dot[LDRUGS];
    #pragma unroll
    for (int d = 0; d < LDRUGS; ++d) dot[d] = 0.f;

    for (int k4 = 0; k4 < 128; ++k4) {
        float4 wv = ld4(&lw[k4 * 4]);
        #pragma unroll
        for (int d = 0; d < LDRUGS; ++d) {
            float4 xv = ld4(&x_l[d * 512 + k4 * 4]);
            dot[d] += wv.x * xv.x + wv.y * xv.y + wv.z * xv.z + wv.w * xv.w;
        }
    }

    const float bb = lin_b[tid];
    #pragma unroll
    for (int d = 0; d < LDRUGS; ++d) {
        if (b0 + d < NB)
            Y[(size_t)(b0 + d) * DD + tid] = fmaxf(dot[d] + bb, 0.f);
    }
}

// ---------------------------------------------------------------------------
// BN stats + apply
// ---------------------------------------------------------------------------
__global__ void bn_stats(const float* __restrict__ Y, float* __restrict__ stats)
{
    int d = blockIdx.x, t = threadIdx.x;
    float s = 0.f, ss = 0.f;
    for (int b = t; b < NB; b += 64) {
        float v = Y[(size_t)b * DD + d];
        s += v; ss += v * v;
    }
    #pragma unroll
    for (int m = 32; m >= 1; m >>= 1) {
        s  += __shfl_xor(s, m, 64);
        ss += __shfl_xor(ss, m, 64);
    }
    if (t == 0) {
        float mean = s * (1.f / NB);
        float var  = ss * (1.f / NB) - mean * mean;
        stats[d]      = mean;
        stats[DD + d] = rsqrtf(var + 1e-5f);
    }
}

__global__ void bn_apply(float* __restrict__ Y, const float* __restrict__ stats,
                         const float* __restrict__ gamma, const float* __restrict__ beta)
{
    int b = blockIdx.x, t = threadIdx.x;
    float mean = stats[t], inv = stats[DD + t];
    float v = Y[(size_t)b * DD + t];
    Y[(size_t)b * DD + t] = gamma[t] * (v - mean) * inv + beta[t];
}

extern "C" void kernel_launch(void* const* d_in, const int* in_sizes, int n_in,
                              void* d_out, int out_size, void* d_ws, size_t ws_size,
                              hipStream_t stream)
{
    const float* drug_table = (const float*)d_in[0];
    const float* rela_table = (const float*)d_in[1];
    const float* ent_table  = (const float*)d_in[2];
    const float* W1         = (const float*)d_in[3];
    const float* b1         = (const float*)d_in[4];
    const float* W2         = (const float*)d_in[5];
    const float* b2         = (const float*)d_in[6];
    const float* lin_w      = (const float*)d_in[7];
    const float* lin_b      = (const float*)d_in[8];
    const float* bn_g       = (const float*)d_in[9];
    const float* bn_b       = (const float*)d_in[10];
    const int*   drug_name  = (const int*)d_in[11];
    const int*   adj_tail   = (const int*)d_in[12];
    const int*   adj_rel    = (const int*)d_in[13];
    float* out = (float*)d_out;

    const int NBP = ((NB + LDRUGS - 1) / LDRUGS) * LDRUGS;   // 576
    float* b2s   = (float*)d_ws;                   // NN
    float* part  = b2s + NN;                       // NB*256
    float* xbuf  = part + (size_t)NB * 256;        // NBP*512
    float* stats = xbuf + (size_t)NBP * 512;       // 2*DD

    sum_b2<<<NN, 64, 0, stream>>>(b2, b2s);
    gnn_mm<<<2 * NB, 512, 0, stream>>>(drug_table, rela_table, W1, b1, W2,
                                       drug_name, adj_rel, part);
    gnn_gather<<<NB, 256, 0, stream>>>(drug_table, ent_table, drug_name,
                                       adj_tail, part, b2s, xbuf);
    gnn_lin<<<NBP / LDRUGS, 256, 0, stream>>>(lin_w, lin_b, xbuf, out);
    bn_stats<<<DD, 64, 0, stream>>>(out, stats);
    bn_apply<<<NB, DD, 0, stream>>>(out, stats, bn_g, bn_b);
}